// Round 7
// baseline (2120.914 us; speedup 1.0000x reference)
//
#include <hip/hip_runtime.h>
#include <cfloat>
#include <cstdint>

#define NPTS 8192
#define NBROWS 16384

typedef unsigned long long u64;
typedef unsigned short ushortT;
typedef __attribute__((ext_vector_type(8))) short short8;
typedef __attribute__((ext_vector_type(4))) float f32x4;

__device__ __forceinline__ unsigned fkey(float f) {
  unsigned u = __float_as_uint(f);
  return (u & 0x80000000u) ? ~u : (u | 0x80000000u);
}
__device__ __forceinline__ float fdecode(unsigned k) {
  unsigned u = (k & 0x80000000u) ? (k ^ 0x80000000u) : ~k;
  return __uint_as_float(u);
}
__device__ __forceinline__ float bf2f(ushortT v) {
  return __uint_as_float(((unsigned)v) << 16);
}
// bf16 RNE round of x; returns bits, sets hf to the rounded-back float.
__device__ __forceinline__ unsigned rne16(float x, float& hf) {
  unsigned u = __float_as_uint(x);
  unsigned r = (u + 0x7FFFu + ((u >> 16) & 1u)) >> 16;
  hf = __uint_as_float(r << 16);
  return r;
}

// Branchless sorted-insert into ascending register list of packed u64 keys.
template <int K>
__device__ __forceinline__ void chain_insert(u64 (&kk)[K], u64 key) {
  #pragma unroll
  for (int q = K - 1; q >= 1; --q) {
    bool cm1 = key < kk[q - 1];
    bool cq  = key < kk[q];
    kk[q] = cm1 ? kk[q - 1] : (cq ? key : kk[q]);
  }
  kk[0] = (key < kk[0]) ? key : kk[0];
}

// ---------------- squared norms of x (C=3) ----------------
__global__ __launch_bounds__(256) void sqx_kernel(const float* __restrict__ x,
                                                  float* __restrict__ sq) {
  int r = blockIdx.x * 256 + threadIdx.x;
  const float* xp = x + (size_t)r * 3;
  sq[r] = fmaf(xp[2], xp[2], fmaf(xp[1], xp[1], xp[0] * xp[0]));
}

// ---------------- knn(k=32) on x + local covariance -> feat12 ----------------
__global__ __launch_bounds__(512, 4) void knn32_cov_kernel(const float* __restrict__ x,
                                                           const float* __restrict__ sqx,
                                                           float* __restrict__ feat) {
  __shared__ __align__(16) unsigned char smem[78080];
  float4* stage4 = (float4*)smem;                        // [2048] 32KB (aliases keyArea)
  unsigned* keyArea = (unsigned*)smem;                   // [512*33]
  unsigned* Trow = (unsigned*)(smem + 67584);            // [32]
  unsigned* cnt  = (unsigned*)(smem + 67712);            // [32]
  u64* apb = (u64*)(smem + 67840);                       // [32*40]

  const int t = threadIdx.x;
  const int r = t & 31, sub = t >> 5;
  const int rowBase = blockIdx.x * 32;
  const int batchBase = rowBase & ~(NPTS - 1);
  const int gRow = rowBase + r;

  const float xi0 = x[(size_t)gRow * 3 + 0];
  const float xi1 = x[(size_t)gRow * 3 + 1];
  const float xi2 = x[(size_t)gRow * 3 + 2];
  const float sqi = sqx[gRow];

  unsigned K[32];
  #pragma unroll
  for (int q = 0; q < 32; ++q) K[q] = 0xFFFFFFFFu;

  for (int round = 0; round < 4; ++round) {
    __syncthreads();
    #pragma unroll
    for (int u = 0; u < 4; ++u) {
      int pp = t + 512 * u;
      int s = pp >> 7, jj = pp & 127;
      int j = s * 512 + round * 128 + jj;
      const float* xp = x + (size_t)(batchBase + j) * 3;
      float4 w;
      w.x = xp[0]; w.y = xp[1]; w.z = xp[2];
      w.w = sqx[batchBase + j];
      stage4[pp] = w;
    }
    __syncthreads();
    const float4* st = stage4 + sub * 128;
    for (int jj = 0; jj < 128; ++jj) {
      float4 w = st[jj];
      float dot = fmaf(xi2, w.z, fmaf(xi1, w.y, xi0 * w.x));
      float d = sqi + w.w - 2.0f * dot;
      unsigned key = fkey(d);
      #pragma unroll
      for (int q = 31; q >= 1; --q) K[q] = max(K[q - 1], min(key, K[q]));
      K[0] = min(key, K[0]);
    }
  }
  __syncthreads();
  {
    const int base = (sub * 32 + r) * 33;
    #pragma unroll
    for (int z = 0; z < 32; ++z) keyArea[base + z] = K[z];
  }
  __syncthreads();
  if (t < 32) {
    cnt[t] = 0u;
    unsigned P[16];
    #pragma unroll
    for (int s = 0; s < 16; ++s) P[s] = 0u;
    unsigned T = 0u;
    for (int step = 0; step < 32; ++step) {
      unsigned best = 0xFFFFFFFFu; int bs = 0;
      #pragma unroll
      for (int s = 0; s < 16; ++s) {
        unsigned v = keyArea[(s * 32 + t) * 33 + P[s]];
        if (v < best) { best = v; bs = s; }
      }
      T = best;
      #pragma unroll
      for (int s = 0; s < 16; ++s) P[s] += (s == bs);
    }
    Trow[t] = T;
  }
  __syncthreads();
  for (int round = 0; round < 4; ++round) {
    __syncthreads();
    #pragma unroll
    for (int u = 0; u < 4; ++u) {
      int pp = t + 512 * u;
      int s = pp >> 7, jj = pp & 127;
      int j = s * 512 + round * 128 + jj;
      const float* xp = x + (size_t)(batchBase + j) * 3;
      float4 w;
      w.x = xp[0]; w.y = xp[1]; w.z = xp[2];
      w.w = sqx[batchBase + j];
      stage4[pp] = w;
    }
    __syncthreads();
    const float4* st = stage4 + sub * 128;
    const unsigned T = Trow[r];
    for (int jj = 0; jj < 128; ++jj) {
      float4 w = st[jj];
      float dot = fmaf(xi2, w.z, fmaf(xi1, w.y, xi0 * w.x));
      float d = sqi + w.w - 2.0f * dot;
      unsigned key = fkey(d);
      if (key <= T) {
        int j = sub * 512 + round * 128 + jj;
        unsigned slot = atomicAdd(&cnt[r], 1u);
        if (slot < 40u) apb[r * 40 + slot] = ((u64)key << 16) | (unsigned)j;
      }
    }
  }
  __syncthreads();
  if (t < 32) {
    int n = (int)cnt[t]; if (n > 40) n = 40;
    u64 kk[32];
    #pragma unroll
    for (int q = 0; q < 32; ++q) kk[q] = ~0ULL;
    for (int i = 0; i < n; ++i) chain_insert<32>(kk, apb[t * 40 + i]);
    float sx = 0.f, sy = 0.f, sz = 0.f;
    #pragma unroll 4
    for (int z = 0; z < 32; ++z) {
      const float* xp = x + (size_t)(batchBase + (int)(kk[z] & 0xFFFFULL)) * 3;
      sx += xp[0]; sy += xp[1]; sz += xp[2];
    }
    const float m0 = sx * (1.f / 32.f), m1 = sy * (1.f / 32.f), m2 = sz * (1.f / 32.f);
    float c00 = 0, c01 = 0, c02 = 0, c11 = 0, c12 = 0, c22 = 0;
    #pragma unroll 4
    for (int z = 0; z < 32; ++z) {
      const float* xp = x + (size_t)(batchBase + (int)(kk[z] & 0xFFFFULL)) * 3;
      float a0 = xp[0] - m0, a1 = xp[1] - m1, a2 = xp[2] - m2;
      c00 = fmaf(a0, a0, c00); c01 = fmaf(a0, a1, c01); c02 = fmaf(a0, a2, c02);
      c11 = fmaf(a1, a1, c11); c12 = fmaf(a1, a2, c12); c22 = fmaf(a2, a2, c22);
    }
    const float inv = 1.f / 32.f;
    float* fp = feat + (size_t)(rowBase + t) * 12;
    fp[0] = xi0; fp[1] = xi1; fp[2] = xi2;
    fp[3] = c00 * inv; fp[4] = c01 * inv; fp[5] = c02 * inv;
    fp[6] = c01 * inv; fp[7] = c11 * inv; fp[8] = c12 * inv;
    fp[9] = c02 * inv; fp[10] = c12 * inv; fp[11] = c22 * inv;
  }
}

// ---------------- feat12 @ W1 -> y (+ per-block BN partials, deterministic) ----------------
__global__ __launch_bounds__(64) void mm12_64_kernel(const float* __restrict__ feat,
                                                     const float* __restrict__ W,
                                                     float* __restrict__ y,
                                                     float* __restrict__ psum,
                                                     float* __restrict__ psq) {
  __shared__ __align__(16) float Ws[12 * 64];
  const int t = threadIdx.x;
  for (int u = t; u < 192; u += 64) ((float4*)Ws)[u] = ((const float4*)W)[u];
  __syncthreads();
  const int row = blockIdx.x * 64 + t;
  float in[12];
  {
    const float4* fp = (const float4*)(feat + (size_t)row * 12);
    float4 a = fp[0], b = fp[1], c = fp[2];
    in[0] = a.x; in[1] = a.y; in[2] = a.z; in[3] = a.w;
    in[4] = b.x; in[5] = b.y; in[6] = b.z; in[7] = b.w;
    in[8] = c.x; in[9] = c.y; in[10] = c.z; in[11] = c.w;
  }
  float acc[64];
  #pragma unroll
  for (int o = 0; o < 64; ++o) acc[o] = 0.f;
  #pragma unroll
  for (int i = 0; i < 12; ++i) {
    const float xi = in[i];
    #pragma unroll
    for (int og = 0; og < 16; ++og) {
      float4 w4 = *(const float4*)(Ws + i * 64 + og * 4);
      acc[og * 4 + 0] = fmaf(xi, w4.x, acc[og * 4 + 0]);
      acc[og * 4 + 1] = fmaf(xi, w4.y, acc[og * 4 + 1]);
      acc[og * 4 + 2] = fmaf(xi, w4.z, acc[og * 4 + 2]);
      acc[og * 4 + 3] = fmaf(xi, w4.w, acc[og * 4 + 3]);
    }
  }
  float4* yp = (float4*)(y + (size_t)row * 64);
  #pragma unroll
  for (int og = 0; og < 16; ++og)
    yp[og] = make_float4(acc[og * 4 + 0], acc[og * 4 + 1], acc[og * 4 + 2], acc[og * 4 + 3]);
  #pragma unroll 1
  for (int o = 0; o < 64; ++o) {
    float s = acc[o], q = acc[o] * acc[o];
    #pragma unroll
    for (int m = 1; m < 64; m <<= 1) { s += __shfl_xor(s, m); q += __shfl_xor(q, m); }
    if (t == 0) { psum[blockIdx.x * 64 + o] = s; psq[blockIdx.x * 64 + o] = q; }
  }
}

// ---------------- generic 64->OUT matmul, optional fused BN+ReLU; per-block partials ----------------
template <int OUT, bool BNRELU>
__global__ __launch_bounds__(64) void mm64_kernel(const float* __restrict__ src,
                                                  const float* __restrict__ W,
                                                  const float* __restrict__ scale,
                                                  const float* __restrict__ shift,
                                                  float* __restrict__ y,
                                                  float* __restrict__ psum,
                                                  float* __restrict__ psq) {
  __shared__ __align__(16) float Ws[64 * OUT];
  const int t = threadIdx.x;
  for (int u = t; u < 16 * OUT; u += 64) ((float4*)Ws)[u] = ((const float4*)W)[u];
  __syncthreads();
  const int row = blockIdx.x * 64 + t;
  float in[64];
  {
    const float4* sp = (const float4*)(src + (size_t)row * 64);
    #pragma unroll
    for (int u = 0; u < 16; ++u) {
      float4 v = sp[u];
      if (BNRELU) {
        v.x = fmaxf(fmaf(v.x, scale[u * 4 + 0], shift[u * 4 + 0]), 0.f);
        v.y = fmaxf(fmaf(v.y, scale[u * 4 + 1], shift[u * 4 + 1]), 0.f);
        v.z = fmaxf(fmaf(v.z, scale[u * 4 + 2], shift[u * 4 + 2]), 0.f);
        v.w = fmaxf(fmaf(v.w, scale[u * 4 + 3], shift[u * 4 + 3]), 0.f);
      }
      in[u * 4 + 0] = v.x; in[u * 4 + 1] = v.y; in[u * 4 + 2] = v.z; in[u * 4 + 3] = v.w;
    }
  }
  for (int half = 0; half < OUT / 64; ++half) {
    float acc[64];
    #pragma unroll
    for (int o = 0; o < 64; ++o) acc[o] = 0.f;
    #pragma unroll 4
    for (int i = 0; i < 64; ++i) {
      const float xi = in[i];
      #pragma unroll
      for (int og = 0; og < 16; ++og) {
        float4 w4 = *(const float4*)(Ws + i * OUT + half * 64 + og * 4);
        acc[og * 4 + 0] = fmaf(xi, w4.x, acc[og * 4 + 0]);
        acc[og * 4 + 1] = fmaf(xi, w4.y, acc[og * 4 + 1]);
        acc[og * 4 + 2] = fmaf(xi, w4.z, acc[og * 4 + 2]);
        acc[og * 4 + 3] = fmaf(xi, w4.w, acc[og * 4 + 3]);
      }
    }
    float4* yp = (float4*)(y + (size_t)row * OUT + half * 64);
    #pragma unroll
    for (int og = 0; og < 16; ++og)
      yp[og] = make_float4(acc[og * 4 + 0], acc[og * 4 + 1], acc[og * 4 + 2], acc[og * 4 + 3]);
    #pragma unroll 1
    for (int o = 0; o < 64; ++o) {
      float s = acc[o], q = acc[o] * acc[o];
      #pragma unroll
      for (int m = 1; m < 64; m <<= 1) { s += __shfl_xor(s, m); q += __shfl_xor(q, m); }
      if (t == 0) {
        psum[blockIdx.x * OUT + half * 64 + o] = s;
        psq[blockIdx.x * OUT + half * 64 + o] = q;
      }
    }
  }
}

// ---------------- deterministic BN finalize from 256 per-block partials ----------------
template <int C>
__global__ void finP_kernel(const float* __restrict__ psum, const float* __restrict__ psq,
                            const float* __restrict__ g, const float* __restrict__ b,
                            float* __restrict__ scale, float* __restrict__ shift) {
  int c = threadIdx.x;
  float s = 0.f, q = 0.f;
  for (int bb = 0; bb < 256; ++bb) { s += psum[bb * C + c]; q += psq[bb * C + c]; }
  float m = s * (1.f / 16384.f);
  float v = q * (1.f / 16384.f) - m * m;
  float sc = g[c] * rsqrtf(v + 1e-5f);
  scale[c] = sc;
  shift[c] = b[c] - m * sc;
}

// ---------------- apply BN + activation; emit 3-term split-bf16 planes + row sq-norm ------
// hbf row record: [C a][C b][C c] bf16 (3C ushorts). a+b+c = x within 2^-27 (nested RNE).
template <int C, bool LEAKY>
__global__ __launch_bounds__(256) void apply_kernel(const float* __restrict__ yraw,
                                                    const float* __restrict__ scale,
                                                    const float* __restrict__ shift,
                                                    ushortT* __restrict__ hbf,
                                                    float* __restrict__ sqout) {
  const int row = blockIdx.x * 256 + threadIdx.x;
  const float4* sp = (const float4*)(yraw + (size_t)row * C);
  ushortT* hb = hbf + (size_t)row * (3 * C);
  float sq = 0.f;
  #pragma unroll
  for (int g = 0; g < C / 8; ++g) {
    float e[8];
    #pragma unroll
    for (int half = 0; half < 2; ++half) {
      float4 v = sp[g * 2 + half];
      const int u = g * 2 + half;
      float4 o;
      o.x = fmaf(v.x, scale[u * 4 + 0], shift[u * 4 + 0]);
      o.y = fmaf(v.y, scale[u * 4 + 1], shift[u * 4 + 1]);
      o.z = fmaf(v.z, scale[u * 4 + 2], shift[u * 4 + 2]);
      o.w = fmaf(v.w, scale[u * 4 + 3], shift[u * 4 + 3]);
      if (LEAKY) {
        o.x = o.x > 0.f ? o.x : 0.01f * o.x;
        o.y = o.y > 0.f ? o.y : 0.01f * o.y;
        o.z = o.z > 0.f ? o.z : 0.01f * o.z;
        o.w = o.w > 0.f ? o.w : 0.01f * o.w;
      } else {
        o.x = fmaxf(o.x, 0.f); o.y = fmaxf(o.y, 0.f);
        o.z = fmaxf(o.z, 0.f); o.w = fmaxf(o.w, 0.f);
      }
      sq = fmaf(o.x, o.x, sq); sq = fmaf(o.y, o.y, sq);
      sq = fmaf(o.z, o.z, sq); sq = fmaf(o.w, o.w, sq);
      e[half * 4 + 0] = o.x; e[half * 4 + 1] = o.y;
      e[half * 4 + 2] = o.z; e[half * 4 + 3] = o.w;
    }
    unsigned pa[8], pb[8], pc[8];
    #pragma unroll
    for (int j = 0; j < 8; ++j) {
      float af, bf, cf;
      pa[j] = rne16(e[j], af);
      float r1 = e[j] - af;
      pb[j] = rne16(r1, bf);
      float r2 = r1 - bf;
      pc[j] = rne16(r2, cf);
    }
    uint4 va, vb, vc;
    va.x = pa[0] | (pa[1] << 16); va.y = pa[2] | (pa[3] << 16);
    va.z = pa[4] | (pa[5] << 16); va.w = pa[6] | (pa[7] << 16);
    vb.x = pb[0] | (pb[1] << 16); vb.y = pb[2] | (pb[3] << 16);
    vb.z = pb[4] | (pb[5] << 16); vb.w = pb[6] | (pb[7] << 16);
    vc.x = pc[0] | (pc[1] << 16); vc.y = pc[2] | (pc[3] << 16);
    vc.z = pc[4] | (pc[5] << 16); vc.w = pc[6] | (pc[7] << 16);
    *(uint4*)(hb + g * 8) = va;
    *(uint4*)(hb + C + g * 8) = vb;
    *(uint4*)(hb + 2 * C + g * 8) = vc;
  }
  sqout[row] = sq;
}

// ---------------- knn(k=8): split-bf16 MFMA distance GEMM -> top-12 per (row,quarter) ------
template <int C>
__global__ __launch_bounds__(256, 3) void knn8_kernel(const ushortT* __restrict__ hbf,
                                                      const float* __restrict__ sqh,
                                                      u64* __restrict__ plist) {
  static_assert(C == 64 || C == 128, "C");
  constexpr int STR = 3 * C + 8;
  constexpr int BSB = 64 * STR * 2;
  constexpr int SMB = BSB > 49152 ? BSB : 49152;   // merge buf needs 32KB; keep >=48K slack
  __shared__ __align__(16) unsigned char smem[SMB];
  ushortT* Bs = (ushortT*)smem;
  u64* mb = (u64*)smem;
  __shared__ float sqB[64];

  const int t = threadIdx.x;
  const int l = t & 63, w = t >> 6;
  const int quad = l >> 4, fif = l & 15;
  const int rg = blockIdx.x >> 2, quarter = blockIdx.x & 3;
  const int rowBase = rg * 64;
  const int batchBase = rowBase & ~(NPTS - 1);

  constexpr int KS = C / 32;
  short8 aa[KS], ab[KS], ac[KS];
  {
    const int arow = rowBase + 16 * w + fif;
    const ushortT* ap = hbf + (size_t)arow * (3 * C);
    #pragma unroll
    for (int s = 0; s < KS; ++s) {
      aa[s] = *(const short8*)(ap + s * 32 + quad * 8);
      ab[s] = *(const short8*)(ap + C + s * 32 + quad * 8);
      ac[s] = *(const short8*)(ap + 2 * C + s * 32 + quad * 8);
    }
  }
  float sqA[4];
  #pragma unroll
  for (int r = 0; r < 4; ++r) sqA[r] = sqh[rowBase + 16 * w + quad * 4 + r];

  u64 L[4][8];
  #pragma unroll
  for (int r = 0; r < 4; ++r)
    #pragma unroll
    for (int z = 0; z < 8; ++z) L[r][z] = ~0ULL;

  constexpr int CPP = C / 8;
  constexpr int LOG = (CPP == 16) ? 4 : 3;

  for (int chunk = 0; chunk < 32; ++chunk) {
    const int cb = quarter * 2048 + chunk * 64;
    __syncthreads();
    {
      #pragma unroll
      for (int p = 0; p < 3; ++p) {
        #pragma unroll
        for (int z = 0; z < (64 * CPP) / 256; ++z) {
          int id = t + 256 * z;
          int col = id >> LOG, ch = id & (CPP - 1);
          uint4 v = *(const uint4*)(hbf + (size_t)(batchBase + cb + col) * (3 * C) + p * C + ch * 8);
          *(uint4*)(Bs + col * STR + p * C + ch * 8) = v;
        }
      }
      if (t < 64) sqB[t] = sqh[batchBase + cb + t];
    }
    __syncthreads();
    #pragma unroll
    for (int tile = 0; tile < 4; ++tile) {
      const int lcol = tile * 16 + fif;
      f32x4 acc0 = {0.f, 0.f, 0.f, 0.f};
      f32x4 acc1 = {0.f, 0.f, 0.f, 0.f};
      f32x4 acc2 = {0.f, 0.f, 0.f, 0.f};
      const ushortT* bp = Bs + lcol * STR + quad * 8;
      #pragma unroll
      for (int s = 0; s < KS; ++s) {
        short8 ba = *(const short8*)(bp + s * 32);
        short8 bb = *(const short8*)(bp + C + s * 32);
        short8 bc = *(const short8*)(bp + 2 * C + s * 32);
        acc0 = __builtin_amdgcn_mfma_f32_16x16x32_bf16(aa[s], ba, acc0, 0, 0, 0);
        acc1 = __builtin_amdgcn_mfma_f32_16x16x32_bf16(aa[s], bb, acc1, 0, 0, 0);
        acc2 = __builtin_amdgcn_mfma_f32_16x16x32_bf16(ab[s], ba, acc2, 0, 0, 0);
        acc0 = __builtin_amdgcn_mfma_f32_16x16x32_bf16(aa[s], bc, acc0, 0, 0, 0);
        acc1 = __builtin_amdgcn_mfma_f32_16x16x32_bf16(ac[s], ba, acc1, 0, 0, 0);
        acc2 = __builtin_amdgcn_mfma_f32_16x16x32_bf16(ab[s], bb, acc2, 0, 0, 0);
      }
      const float sb = sqB[lcol];
      const unsigned gcol = (unsigned)(cb + lcol);
      #pragma unroll
      for (int r = 0; r < 4; ++r) {
        float dot = acc0[r] + acc1[r] + acc2[r];
        float d = sqA[r] + sb - 2.0f * dot;
        u64 key = ((u64)fkey(d) << 16) | gcol;
        chain_insert<8>(L[r], key);
      }
    }
  }
  // 16-way merge per row -> top-12, two 32-row passes (mb aliases Bs)
  for (int rh = 0; rh < 2; ++rh) {
    __syncthreads();
    if ((w >> 1) == rh) {
      #pragma unroll
      for (int r = 0; r < 4; ++r) {
        int lr = (16 * w + quad * 4 + r) & 31;
        #pragma unroll
        for (int z = 0; z < 8; ++z) mb[(lr * 16 + fif) * 8 + z] = L[r][z];
      }
    }
    __syncthreads();
    if (t < 32) {
      int ps[16];
      #pragma unroll
      for (int s = 0; s < 16; ++s) ps[s] = 0;
      u64 outk[12];
      for (int z = 0; z < 12; ++z) {
        u64 best = ~0ULL; int bs = 0;
        #pragma unroll
        for (int s = 0; s < 16; ++s) {
          u64 v = (ps[s] < 8) ? mb[(t * 16 + s) * 8 + ps[s]] : ~0ULL;
          if (v < best) { best = v; bs = s; }
        }
        outk[z] = best;
        #pragma unroll
        for (int s = 0; s < 16; ++s) ps[s] += (s == bs);
      }
      u64* dst = plist + ((size_t)(rowBase + rh * 32 + t) * 4 + quarter) * 12;
      #pragma unroll
      for (int z = 0; z < 12; ++z) dst[z] = outk[z];
    }
  }
}

// ---------------- exact fp32 re-rank of 48 candidates + top-8 + fused gather-max ----------
// block 256 = 4 waves, one row per wave. Deterministic wave-min extraction.
template <int C>
__global__ __launch_bounds__(256) void knn8rf_kernel(const u64* __restrict__ plist,
                                                     const ushortT* __restrict__ hbf,
                                                     const float* __restrict__ sqh,
                                                     float* __restrict__ nout) {
  __shared__ float xiL[4][C];
  const int t = threadIdx.x;
  const int w = t >> 6, l = t & 63;
  const int row = blockIdx.x * 4 + w;
  const int batchBase = row & ~(NPTS - 1);
  {
    const ushortT* src = hbf + (size_t)row * (3 * C);
    #pragma unroll
    for (int u = 0; u < C / 64; ++u) {
      int ch = l + u * 64;
      float av = bf2f(src[ch]), bv = bf2f(src[C + ch]), cv = bf2f(src[2 * C + ch]);
      xiL[w][ch] = av + (bv + cv);
    }
  }
  __syncthreads();
  const float sqi = sqh[row];
  const u64* pl = plist + (size_t)row * 48;
  u64 myk = ~0ULL;
  if (l < 48) {
    int cand = (int)(pl[l] & 0xFFFFULL) & (NPTS - 1);
    const ushortT* sp = hbf + (size_t)(batchBase + cand) * (3 * C);
    float dot = 0.f;
    #pragma unroll 4
    for (int kk = 0; kk < C; kk += 2) {
      unsigned ua = *(const unsigned*)(sp + kk);
      unsigned ub = *(const unsigned*)(sp + C + kk);
      unsigned uc = *(const unsigned*)(sp + 2 * C + kk);
      float a0 = __uint_as_float(ua << 16), a1 = __uint_as_float(ua & 0xFFFF0000u);
      float b0 = __uint_as_float(ub << 16), b1 = __uint_as_float(ub & 0xFFFF0000u);
      float c0 = __uint_as_float(uc << 16), c1 = __uint_as_float(uc & 0xFFFF0000u);
      float x0 = a0 + (b0 + c0), x1 = a1 + (b1 + c1);
      dot = fmaf(xiL[w][kk], x0, dot);
      dot = fmaf(xiL[w][kk + 1], x1, dot);
    }
    float d = sqi + sqh[batchBase + cand] - 2.0f * dot;
    myk = ((u64)fkey(d) << 16) | (unsigned)cand;
  }
  u64 top[8];
  #pragma unroll
  for (int z = 0; z < 8; ++z) {
    u64 m = myk;
    #pragma unroll
    for (int off = 1; off < 64; off <<= 1) {
      u64 o = (u64)__shfl_xor((long long)m, off);
      m = o < m ? o : m;
    }
    top[z] = m;
    if (myk == m) myk = ~0ULL;
  }
  constexpr int PER = C / 64;
  float mx[PER];
  #pragma unroll
  for (int u = 0; u < PER; ++u) mx[u] = -FLT_MAX;
  #pragma unroll
  for (int z = 0; z < 8; ++z) {
    int idx = (int)(top[z] & 0xFFFFULL) & (NPTS - 1);
    const ushortT* src = hbf + (size_t)(batchBase + idx) * (3 * C);
    #pragma unroll
    for (int u = 0; u < PER; ++u) {
      int ch = l + u * 64;
      float av = bf2f(src[ch]), bv = bf2f(src[C + ch]), cv = bf2f(src[2 * C + ch]);
      float xv = av + (bv + cv);
      mx[u] = fmaxf(mx[u], xv);
    }
  }
  float* dst = nout + (size_t)row * C;
  #pragma unroll
  for (int u = 0; u < PER; ++u) dst[l + u * 64] = mx[u];
}

// ---------------- n2[16384,128] @ gW2[128,1024]: deterministic stats partials + atomicMax ----------------
__global__ __launch_bounds__(256) void mmE_kernel(const float* __restrict__ n2,
                                                  const float* __restrict__ W,
                                                  float* __restrict__ psum,
                                                  float* __restrict__ psq,
                                                  unsigned* __restrict__ gmax) {
  __shared__ __align__(16) float As[64 * 64];
  __shared__ __align__(16) float Bs[64 * 64];
  __shared__ float sP[16 * 64];
  __shared__ float qP[16 * 64];
  __shared__ float mP[16 * 64];
  const int t = threadIdx.x;
  const int rowStripe = blockIdx.x >> 4;
  const int colStripe = blockIdx.x & 15;
  const int rowBase = rowStripe * 64;
  const int colBase = colStripe * 64;
  const int batch = rowBase >> 13;
  const int tx = t & 15, ty = t >> 4;

  float acc[16];
  #pragma unroll
  for (int q = 0; q < 16; ++q) acc[q] = 0.f;

  for (int kh = 0; kh < 2; ++kh) {
    __syncthreads();
    {
      const int ar = t & 63;
      const int k0 = (t >> 6) * 16;
      const float* src = n2 + (size_t)(rowBase + ar) * 128 + kh * 64 + k0;
      #pragma unroll
      for (int kk = 0; kk < 16; kk += 4) {
        float4 v = *(const float4*)(src + kk);
        As[(k0 + kk + 0) * 64 + ar] = v.x;
        As[(k0 + kk + 1) * 64 + ar] = v.y;
        As[(k0 + kk + 2) * 64 + ar] = v.z;
        As[(k0 + kk + 3) * 64 + ar] = v.w;
      }
    }
    {
      #pragma unroll
      for (int z = 0; z < 4; ++z) {
        int u = t + 256 * z;
        int k = u >> 4, c4 = u & 15;
        float4 v = *(const float4*)(W + (size_t)(kh * 64 + k) * 1024 + colBase + c4 * 4);
        *(float4*)(Bs + k * 64 + c4 * 4) = v;
      }
    }
    __syncthreads();
    #pragma unroll 4
    for (int k = 0; k < 64; ++k) {
      float4 a4 = *(const float4*)(As + k * 64 + ty * 4);
      float4 b4 = *(const float4*)(Bs + k * 64 + tx * 4);
      acc[0] = fmaf(a4.x, b4.x, acc[0]);   acc[1] = fmaf(a4.x, b4.y, acc[1]);
      acc[2] = fmaf(a4.x, b4.z, acc[2]);   acc[3] = fmaf(a4.x, b4.w, acc[3]);
      acc[4] = fmaf(a4.y, b4.x, acc[4]);   acc[5] = fmaf(a4.y, b4.y, acc[5]);
      acc[6] = fmaf(a4.y, b4.z, acc[6]);   acc[7] = fmaf(a4.y, b4.w, acc[7]);
      acc[8] = fmaf(a4.z, b4.x, acc[8]);   acc[9] = fmaf(a4.z, b4.y, acc[9]);
      acc[10] = fmaf(a4.z, b4.z, acc[10]); acc[11] = fmaf(a4.z, b4.w, acc[11]);
      acc[12] = fmaf(a4.w, b4.x, acc[12]); acc[13] = fmaf(a4.w, b4.y, acc[13]);
      acc[14] = fmaf(a4.w, b4.z, acc[14]); acc[15] = fmaf(a4.w, b4.w, acc[15]);
    }
  }
  #pragma unroll
  for (int p = 0; p < 4; ++p) {
    float s = 0.f, q = 0.f, m = -FLT_MAX;
    #pragma unroll
    for (int qq = 0; qq < 4; ++qq) {
      float v = acc[qq * 4 + p];
      s += v; q = fmaf(v, v, q); m = fmaxf(m, v);
    }
    sP[ty * 64 + tx * 4 + p] = s;
    qP[ty * 64 + tx * 4 + p] = q;
    mP[ty * 64 + tx * 4 + p] = m;
  }
  __syncthreads();
  if (t < 64) {
    float s = 0.f, q = 0.f, m = -FLT_MAX;
    #pragma unroll
    for (int u = 0; u < 16; ++u) {
      s += sP[u * 64 + t];
      q += qP[u * 64 + t];
      m = fmaxf(m, mP[u * 64 + t]);
    }
    psum[rowStripe * 1024 + colBase + t] = s;
    psq [rowStripe * 1024 + colBase + t] = q;
    atomicMax(&gmax[batch * 1024 + colBase + t], fkey(m));
  }
}

// ---------------- BN4 finalize (deterministic stripe sum) + leaky on pooled max ----------------
__global__ void poolbn_kernel(const float* __restrict__ psumE, const float* __restrict__ psqE,
                              const unsigned* __restrict__ gmax,
                              const float* __restrict__ gg2, const float* __restrict__ gb2,
                              float* __restrict__ fpool) {
  int c = threadIdx.x;
  float s = 0.f, q = 0.f;
  for (int bb = 0; bb < 256; ++bb) { s += psumE[bb * 1024 + c]; q += psqE[bb * 1024 + c]; }
  float m = s * (1.f / 16384.f);
  float v = q * (1.f / 16384.f) - m * m;
  float sc = gg2[c] * rsqrtf(v + 1e-5f);
  float sh = gb2[c] - m * sc;
  #pragma unroll
  for (int b = 0; b < 2; ++b) {
    float raw = fdecode(gmax[b * 1024 + c]);
    float t = fmaf(raw, sc, sh);
    fpool[b * 1024 + c] = t > 0.f ? t : 0.01f * t;
  }
}

// ---------------- fpool @ W4 + BN over 2 samples + relu -> out ----------------
__global__ __launch_bounds__(64) void final_kernel(const float* __restrict__ fpool,
                                                   const float* __restrict__ W4,
                                                   const float* __restrict__ g4,
                                                   const float* __restrict__ b4f,
                                                   float* __restrict__ out) {
  const int o = blockIdx.x * 64 + threadIdx.x;
  float a0 = 0.f, a1 = 0.f;
  for (int c = 0; c < 1024; ++c) {
    float w = W4[(size_t)c * 512 + o];
    a0 = fmaf(fpool[c], w, a0);
    a1 = fmaf(fpool[1024 + c], w, a1);
  }
  float m = 0.5f * (a0 + a1);
  float d0 = a0 - m, d1 = a1 - m;
  float v = 0.5f * (d0 * d0 + d1 * d1);
  float r = rsqrtf(v + 1e-5f);
  float o0 = fmaf(d0 * r, g4[o], b4f[o]);
  float o1 = fmaf(d1 * r, g4[o], b4f[o]);
  out[o] = fmaxf(o0, 0.f);
  out[512 + o] = fmaxf(o1, 0.f);
}

extern "C" void kernel_launch(void* const* d_in, const int* in_sizes, int n_in,
                              void* d_out, int out_size, void* d_ws, size_t ws_size,
                              hipStream_t stream) {
  (void)in_sizes; (void)n_in; (void)out_size; (void)ws_size;
  const float* x   = (const float*)d_in[0];
  const float* W1  = (const float*)d_in[1];
  const float* g1  = (const float*)d_in[2];
  const float* b1  = (const float*)d_in[3];
  const float* W2  = (const float*)d_in[4];
  const float* g2  = (const float*)d_in[5];
  const float* b2  = (const float*)d_in[6];
  const float* W3  = (const float*)d_in[7];
  const float* g3  = (const float*)d_in[8];
  const float* b3  = (const float*)d_in[9];
  const float* gW1 = (const float*)d_in[10];
  const float* gg1 = (const float*)d_in[11];
  const float* gb1 = (const float*)d_in[12];
  const float* gW2 = (const float*)d_in[13];
  const float* gg2 = (const float*)d_in[14];
  const float* gb2 = (const float*)d_in[15];
  const float* W4  = (const float*)d_in[16];
  const float* g4  = (const float*)d_in[17];
  const float* b4  = (const float*)d_in[18];
  float* out = (float*)d_out;
  float* ws = (float*)d_ws;

  // footprint identical to the R4-proven 30.49 MB layout
  float* sqx  = ws;                    // 16384
  float* feat = sqx + 16384;           // 196608 (later: p2/p3/p4 stats)
  float* bufA = feat + 196608;         // 1048576
  float* bufB = bufA + 1048576;        // 1048576 (bufA+bufB also hold plist 6.3MB)
  float* sqh  = bufB + 1048576;        // 16384
  float* sqg  = sqh + 16384;           // 16384
  float* ygr  = sqg + 16384;           // 2097152 (yg1 raw -> n2)
  float* hbfR = ygr + 2097152;         // 3145728 (hbf1 [+n1 after it]; hbf2 overwrites)
  float* st   = hbfR + 3145728;

  unsigned* gmax = (unsigned*)(st);            // 2048 uints
  float* scale0 = st + 2048;  float* shift0 = st + 2112;
  float* scale1 = st + 2176;  float* shift1 = st + 2240;
  float* scale2 = st + 2304;  float* shift2 = st + 2368;
  float* scale3 = st + 2432;  float* shift3 = st + 2560;
  float* fpool  = st + 2688;                   // 2048
  float* p1s    = st + 4736;                   // 256*64
  float* p1q    = p1s + 16384;                 // ends st+37504

  float* p2s = feat;             float* p2q = feat + 16384;
  float* p3s = feat + 32768;     float* p3q = feat + 49152;
  float* p4s = feat;             float* p4q = feat + 32768;     // reused after p2/p3 dead
  float* pEs = bufA;             float* pEq = bufA + 262144;
  u64* plist = (u64*)bufA;                     // 16384*48 u64 = 6.3MB (bufA+bufB span)

  ushortT* hbf1 = (ushortT*)hbfR;              // 16384 x 192 ushorts (1,572,864 floats)
  ushortT* hbf2 = (ushortT*)hbfR;              // 16384 x 384 ushorts (full region)
  float* n1 = hbfR + 1572864;                  // 1,048,576 floats after hbf1
  float* n2 = ygr;

  hipMemsetAsync(gmax, 0, 2048 * sizeof(unsigned), stream);
  sqx_kernel<<<64, 256, 0, stream>>>(x, sqx);
  knn32_cov_kernel<<<512, 512, 0, stream>>>(x, sqx, feat);
  mm12_64_kernel<<<256, 64, 0, stream>>>(feat, W1, bufA, p1s, p1q);
  finP_kernel<64><<<1, 64, 0, stream>>>(p1s, p1q, g1, b1, scale0, shift0);
  mm64_kernel<64, true><<<256, 64, 0, stream>>>(bufA, W2, scale0, shift0, bufB, p2s, p2q);
  finP_kernel<64><<<1, 64, 0, stream>>>(p2s, p2q, g2, b2, scale1, shift1);
  mm64_kernel<64, true><<<256, 64, 0, stream>>>(bufB, W3, scale1, shift1, bufA, p3s, p3q);
  finP_kernel<64><<<1, 64, 0, stream>>>(p3s, p3q, g3, b3, scale2, shift2);
  apply_kernel<64, false><<<64, 256, 0, stream>>>(bufA, scale2, shift2, hbf1, sqh);
  knn8_kernel<64><<<1024, 256, 0, stream>>>(hbf1, sqh, plist);
  knn8rf_kernel<64><<<4096, 256, 0, stream>>>(plist, hbf1, sqh, n1);
  mm64_kernel<128, false><<<256, 64, 0, stream>>>(n1, gW1, scale0, shift0, ygr, p4s, p4q);
  finP_kernel<128><<<1, 128, 0, stream>>>(p4s, p4q, gg1, gb1, scale3, shift3);
  apply_kernel<128, true><<<64, 256, 0, stream>>>(ygr, scale3, shift3, hbf2, sqg);
  knn8_kernel<128><<<1024, 256, 0, stream>>>(hbf2, sqg, plist);
  knn8rf_kernel<128><<<4096, 256, 0, stream>>>(plist, hbf2, sqg, n2);
  mmE_kernel<<<4096, 256, 0, stream>>>(n2, gW2, pEs, pEq, gmax);
  poolbn_kernel<<<1, 1024, 0, stream>>>(pEs, pEq, gmax, gg2, gb2, fpool);
  final_kernel<<<8, 64, 0, stream>>>(fpool, W4, g4, b4, out);
}

// Round 8
// 2120.285 us; speedup vs baseline: 1.0003x; 1.0003x over previous
//
#include <hip/hip_runtime.h>
#include <cfloat>
#include <cstdint>

#define NPTS 8192
#define NBROWS 16384

typedef unsigned long long u64;
typedef unsigned short ushortT;
typedef __attribute__((ext_vector_type(8))) short short8;
typedef __attribute__((ext_vector_type(4))) float f32x4;

__device__ __forceinline__ unsigned fkey(float f) {
  unsigned u = __float_as_uint(f);
  return (u & 0x80000000u) ? ~u : (u | 0x80000000u);
}
__device__ __forceinline__ float fdecode(unsigned k) {
  unsigned u = (k & 0x80000000u) ? (k ^ 0x80000000u) : ~k;
  return __uint_as_float(u);
}
__device__ __forceinline__ float bf2f(ushortT v) {
  return __uint_as_float(((unsigned)v) << 16);
}
// bf16 RNE round of x; returns bits, sets hf to the rounded-back float.
__device__ __forceinline__ unsigned rne16(float x, float& hf) {
  unsigned u = __float_as_uint(x);
  unsigned r = (u + 0x7FFFu + ((u >> 16) & 1u)) >> 16;
  hf = __uint_as_float(r << 16);
  return r;
}

// Branchless sorted-insert into ascending register list of packed u64 keys.
template <int K>
__device__ __forceinline__ void chain_insert(u64 (&kk)[K], u64 key) {
  #pragma unroll
  for (int q = K - 1; q >= 1; --q) {
    bool cm1 = key < kk[q - 1];
    bool cq  = key < kk[q];
    kk[q] = cm1 ? kk[q - 1] : (cq ? key : kk[q]);
  }
  kk[0] = (key < kk[0]) ? key : kk[0];
}

// ---------------- squared norms of x (C=3) ----------------
__global__ __launch_bounds__(256) void sqx_kernel(const float* __restrict__ x,
                                                  float* __restrict__ sq) {
  int r = blockIdx.x * 256 + threadIdx.x;
  const float* xp = x + (size_t)r * 3;
  sq[r] = fmaf(xp[2], xp[2], fmaf(xp[1], xp[1], xp[0] * xp[0]));
}

// ---------------- knn(k=32) on x + local covariance -> feat12 ----------------
__global__ __launch_bounds__(512, 4) void knn32_cov_kernel(const float* __restrict__ x,
                                                           const float* __restrict__ sqx,
                                                           float* __restrict__ feat) {
  __shared__ __align__(16) unsigned char smem[78080];
  float4* stage4 = (float4*)smem;                        // [2048] 32KB (aliases keyArea)
  unsigned* keyArea = (unsigned*)smem;                   // [512*33]
  unsigned* Trow = (unsigned*)(smem + 67584);            // [32]
  unsigned* cnt  = (unsigned*)(smem + 67712);            // [32]
  u64* apb = (u64*)(smem + 67840);                       // [32*40]

  const int t = threadIdx.x;
  const int r = t & 31, sub = t >> 5;
  const int rowBase = blockIdx.x * 32;
  const int batchBase = rowBase & ~(NPTS - 1);
  const int gRow = rowBase + r;

  const float xi0 = x[(size_t)gRow * 3 + 0];
  const float xi1 = x[(size_t)gRow * 3 + 1];
  const float xi2 = x[(size_t)gRow * 3 + 2];
  const float sqi = sqx[gRow];

  unsigned K[32];
  #pragma unroll
  for (int q = 0; q < 32; ++q) K[q] = 0xFFFFFFFFu;

  for (int round = 0; round < 4; ++round) {
    __syncthreads();
    #pragma unroll
    for (int u = 0; u < 4; ++u) {
      int pp = t + 512 * u;
      int s = pp >> 7, jj = pp & 127;
      int j = s * 512 + round * 128 + jj;
      const float* xp = x + (size_t)(batchBase + j) * 3;
      float4 w;
      w.x = xp[0]; w.y = xp[1]; w.z = xp[2];
      w.w = sqx[batchBase + j];
      stage4[pp] = w;
    }
    __syncthreads();
    const float4* st = stage4 + sub * 128;
    for (int jj = 0; jj < 128; ++jj) {
      float4 w = st[jj];
      float dot = fmaf(xi2, w.z, fmaf(xi1, w.y, xi0 * w.x));
      float d = sqi + w.w - 2.0f * dot;
      unsigned key = fkey(d);
      #pragma unroll
      for (int q = 31; q >= 1; --q) K[q] = max(K[q - 1], min(key, K[q]));
      K[0] = min(key, K[0]);
    }
  }
  __syncthreads();
  {
    const int base = (sub * 32 + r) * 33;
    #pragma unroll
    for (int z = 0; z < 32; ++z) keyArea[base + z] = K[z];
  }
  __syncthreads();
  if (t < 32) {
    cnt[t] = 0u;
    unsigned P[16];
    #pragma unroll
    for (int s = 0; s < 16; ++s) P[s] = 0u;
    unsigned T = 0u;
    for (int step = 0; step < 32; ++step) {
      unsigned best = 0xFFFFFFFFu; int bs = 0;
      #pragma unroll
      for (int s = 0; s < 16; ++s) {
        unsigned v = keyArea[(s * 32 + t) * 33 + P[s]];
        if (v < best) { best = v; bs = s; }
      }
      T = best;
      #pragma unroll
      for (int s = 0; s < 16; ++s) P[s] += (s == bs);
    }
    Trow[t] = T;
  }
  __syncthreads();
  for (int round = 0; round < 4; ++round) {
    __syncthreads();
    #pragma unroll
    for (int u = 0; u < 4; ++u) {
      int pp = t + 512 * u;
      int s = pp >> 7, jj = pp & 127;
      int j = s * 512 + round * 128 + jj;
      const float* xp = x + (size_t)(batchBase + j) * 3;
      float4 w;
      w.x = xp[0]; w.y = xp[1]; w.z = xp[2];
      w.w = sqx[batchBase + j];
      stage4[pp] = w;
    }
    __syncthreads();
    const float4* st = stage4 + sub * 128;
    const unsigned T = Trow[r];
    for (int jj = 0; jj < 128; ++jj) {
      float4 w = st[jj];
      float dot = fmaf(xi2, w.z, fmaf(xi1, w.y, xi0 * w.x));
      float d = sqi + w.w - 2.0f * dot;
      unsigned key = fkey(d);
      if (key <= T) {
        int j = sub * 512 + round * 128 + jj;
        unsigned slot = atomicAdd(&cnt[r], 1u);
        if (slot < 40u) apb[r * 40 + slot] = ((u64)key << 16) | (unsigned)j;
      }
    }
  }
  __syncthreads();
  if (t < 32) {
    int n = (int)cnt[t]; if (n > 40) n = 40;
    u64 kk[32];
    #pragma unroll
    for (int q = 0; q < 32; ++q) kk[q] = ~0ULL;
    for (int i = 0; i < n; ++i) chain_insert<32>(kk, apb[t * 40 + i]);
    float sx = 0.f, sy = 0.f, sz = 0.f;
    #pragma unroll 4
    for (int z = 0; z < 32; ++z) {
      const float* xp = x + (size_t)(batchBase + (int)(kk[z] & 0xFFFFULL)) * 3;
      sx += xp[0]; sy += xp[1]; sz += xp[2];
    }
    const float m0 = sx * (1.f / 32.f), m1 = sy * (1.f / 32.f), m2 = sz * (1.f / 32.f);
    float c00 = 0, c01 = 0, c02 = 0, c11 = 0, c12 = 0, c22 = 0;
    #pragma unroll 4
    for (int z = 0; z < 32; ++z) {
      const float* xp = x + (size_t)(batchBase + (int)(kk[z] & 0xFFFFULL)) * 3;
      float a0 = xp[0] - m0, a1 = xp[1] - m1, a2 = xp[2] - m2;
      c00 = fmaf(a0, a0, c00); c01 = fmaf(a0, a1, c01); c02 = fmaf(a0, a2, c02);
      c11 = fmaf(a1, a1, c11); c12 = fmaf(a1, a2, c12); c22 = fmaf(a2, a2, c22);
    }
    const float inv = 1.f / 32.f;
    float* fp = feat + (size_t)(rowBase + t) * 12;
    fp[0] = xi0; fp[1] = xi1; fp[2] = xi2;
    fp[3] = c00 * inv; fp[4] = c01 * inv; fp[5] = c02 * inv;
    fp[6] = c01 * inv; fp[7] = c11 * inv; fp[8] = c12 * inv;
    fp[9] = c02 * inv; fp[10] = c12 * inv; fp[11] = c22 * inv;
  }
}

// ---------------- feat12 @ W1 -> y (+ per-block BN partials, deterministic) ----------------
__global__ __launch_bounds__(64) void mm12_64_kernel(const float* __restrict__ feat,
                                                     const float* __restrict__ W,
                                                     float* __restrict__ y,
                                                     float* __restrict__ psum,
                                                     float* __restrict__ psq) {
  __shared__ __align__(16) float Ws[12 * 64];
  const int t = threadIdx.x;
  for (int u = t; u < 192; u += 64) ((float4*)Ws)[u] = ((const float4*)W)[u];
  __syncthreads();
  const int row = blockIdx.x * 64 + t;
  float in[12];
  {
    const float4* fp = (const float4*)(feat + (size_t)row * 12);
    float4 a = fp[0], b = fp[1], c = fp[2];
    in[0] = a.x; in[1] = a.y; in[2] = a.z; in[3] = a.w;
    in[4] = b.x; in[5] = b.y; in[6] = b.z; in[7] = b.w;
    in[8] = c.x; in[9] = c.y; in[10] = c.z; in[11] = c.w;
  }
  float acc[64];
  #pragma unroll
  for (int o = 0; o < 64; ++o) acc[o] = 0.f;
  #pragma unroll
  for (int i = 0; i < 12; ++i) {
    const float xi = in[i];
    #pragma unroll
    for (int og = 0; og < 16; ++og) {
      float4 w4 = *(const float4*)(Ws + i * 64 + og * 4);
      acc[og * 4 + 0] = fmaf(xi, w4.x, acc[og * 4 + 0]);
      acc[og * 4 + 1] = fmaf(xi, w4.y, acc[og * 4 + 1]);
      acc[og * 4 + 2] = fmaf(xi, w4.z, acc[og * 4 + 2]);
      acc[og * 4 + 3] = fmaf(xi, w4.w, acc[og * 4 + 3]);
    }
  }
  float4* yp = (float4*)(y + (size_t)row * 64);
  #pragma unroll
  for (int og = 0; og < 16; ++og)
    yp[og] = make_float4(acc[og * 4 + 0], acc[og * 4 + 1], acc[og * 4 + 2], acc[og * 4 + 3]);
  #pragma unroll 1
  for (int o = 0; o < 64; ++o) {
    float s = acc[o], q = acc[o] * acc[o];
    #pragma unroll
    for (int m = 1; m < 64; m <<= 1) { s += __shfl_xor(s, m); q += __shfl_xor(q, m); }
    if (t == 0) { psum[blockIdx.x * 64 + o] = s; psq[blockIdx.x * 64 + o] = q; }
  }
}

// ---------------- generic 64->OUT matmul, optional fused BN+ReLU; per-block partials ----------------
template <int OUT, bool BNRELU>
__global__ __launch_bounds__(64) void mm64_kernel(const float* __restrict__ src,
                                                  const float* __restrict__ W,
                                                  const float* __restrict__ scale,
                                                  const float* __restrict__ shift,
                                                  float* __restrict__ y,
                                                  float* __restrict__ psum,
                                                  float* __restrict__ psq) {
  __shared__ __align__(16) float Ws[64 * OUT];
  const int t = threadIdx.x;
  for (int u = t; u < 16 * OUT; u += 64) ((float4*)Ws)[u] = ((const float4*)W)[u];
  __syncthreads();
  const int row = blockIdx.x * 64 + t;
  float in[64];
  {
    const float4* sp = (const float4*)(src + (size_t)row * 64);
    #pragma unroll
    for (int u = 0; u < 16; ++u) {
      float4 v = sp[u];
      if (BNRELU) {
        v.x = fmaxf(fmaf(v.x, scale[u * 4 + 0], shift[u * 4 + 0]), 0.f);
        v.y = fmaxf(fmaf(v.y, scale[u * 4 + 1], shift[u * 4 + 1]), 0.f);
        v.z = fmaxf(fmaf(v.z, scale[u * 4 + 2], shift[u * 4 + 2]), 0.f);
        v.w = fmaxf(fmaf(v.w, scale[u * 4 + 3], shift[u * 4 + 3]), 0.f);
      }
      in[u * 4 + 0] = v.x; in[u * 4 + 1] = v.y; in[u * 4 + 2] = v.z; in[u * 4 + 3] = v.w;
    }
  }
  for (int half = 0; half < OUT / 64; ++half) {
    float acc[64];
    #pragma unroll
    for (int o = 0; o < 64; ++o) acc[o] = 0.f;
    #pragma unroll 4
    for (int i = 0; i < 64; ++i) {
      const float xi = in[i];
      #pragma unroll
      for (int og = 0; og < 16; ++og) {
        float4 w4 = *(const float4*)(Ws + i * OUT + half * 64 + og * 4);
        acc[og * 4 + 0] = fmaf(xi, w4.x, acc[og * 4 + 0]);
        acc[og * 4 + 1] = fmaf(xi, w4.y, acc[og * 4 + 1]);
        acc[og * 4 + 2] = fmaf(xi, w4.z, acc[og * 4 + 2]);
        acc[og * 4 + 3] = fmaf(xi, w4.w, acc[og * 4 + 3]);
      }
    }
    float4* yp = (float4*)(y + (size_t)row * OUT + half * 64);
    #pragma unroll
    for (int og = 0; og < 16; ++og)
      yp[og] = make_float4(acc[og * 4 + 0], acc[og * 4 + 1], acc[og * 4 + 2], acc[og * 4 + 3]);
    #pragma unroll 1
    for (int o = 0; o < 64; ++o) {
      float s = acc[o], q = acc[o] * acc[o];
      #pragma unroll
      for (int m = 1; m < 64; m <<= 1) { s += __shfl_xor(s, m); q += __shfl_xor(q, m); }
      if (t == 0) {
        psum[blockIdx.x * OUT + half * 64 + o] = s;
        psq[blockIdx.x * OUT + half * 64 + o] = q;
      }
    }
  }
}

// ---------------- deterministic BN finalize from 256 per-block partials ----------------
template <int C>
__global__ void finP_kernel(const float* __restrict__ psum, const float* __restrict__ psq,
                            const float* __restrict__ g, const float* __restrict__ b,
                            float* __restrict__ scale, float* __restrict__ shift) {
  int c = threadIdx.x;
  float s = 0.f, q = 0.f;
  for (int bb = 0; bb < 256; ++bb) { s += psum[bb * C + c]; q += psq[bb * C + c]; }
  float m = s * (1.f / 16384.f);
  float v = q * (1.f / 16384.f) - m * m;
  float sc = g[c] * rsqrtf(v + 1e-5f);
  scale[c] = sc;
  shift[c] = b[c] - m * sc;
}

// ---------------- apply BN + activation; 3-term split: planes a,b -> hab; plane c -> hc ---
// hab row record: [C a][C b]; hc row record: [C c]. a+b+c = x within 2^-27 (nested RNE).
template <int C, bool LEAKY>
__global__ __launch_bounds__(256) void apply_kernel(const float* __restrict__ yraw,
                                                    const float* __restrict__ scale,
                                                    const float* __restrict__ shift,
                                                    ushortT* __restrict__ hab,
                                                    ushortT* __restrict__ hc,
                                                    float* __restrict__ sqout) {
  const int row = blockIdx.x * 256 + threadIdx.x;
  const float4* sp = (const float4*)(yraw + (size_t)row * C);
  ushortT* hb = hab + (size_t)row * (2 * C);
  ushortT* hcp = hc + (size_t)row * C;
  float sq = 0.f;
  #pragma unroll
  for (int g = 0; g < C / 8; ++g) {
    float e[8];
    #pragma unroll
    for (int half = 0; half < 2; ++half) {
      float4 v = sp[g * 2 + half];
      const int u = g * 2 + half;
      float4 o;
      o.x = fmaf(v.x, scale[u * 4 + 0], shift[u * 4 + 0]);
      o.y = fmaf(v.y, scale[u * 4 + 1], shift[u * 4 + 1]);
      o.z = fmaf(v.z, scale[u * 4 + 2], shift[u * 4 + 2]);
      o.w = fmaf(v.w, scale[u * 4 + 3], shift[u * 4 + 3]);
      if (LEAKY) {
        o.x = o.x > 0.f ? o.x : 0.01f * o.x;
        o.y = o.y > 0.f ? o.y : 0.01f * o.y;
        o.z = o.z > 0.f ? o.z : 0.01f * o.z;
        o.w = o.w > 0.f ? o.w : 0.01f * o.w;
      } else {
        o.x = fmaxf(o.x, 0.f); o.y = fmaxf(o.y, 0.f);
        o.z = fmaxf(o.z, 0.f); o.w = fmaxf(o.w, 0.f);
      }
      sq = fmaf(o.x, o.x, sq); sq = fmaf(o.y, o.y, sq);
      sq = fmaf(o.z, o.z, sq); sq = fmaf(o.w, o.w, sq);
      e[half * 4 + 0] = o.x; e[half * 4 + 1] = o.y;
      e[half * 4 + 2] = o.z; e[half * 4 + 3] = o.w;
    }
    unsigned pa[8], pb[8], pc[8];
    #pragma unroll
    for (int j = 0; j < 8; ++j) {
      float af, bf, cf;
      pa[j] = rne16(e[j], af);
      float r1 = e[j] - af;
      pb[j] = rne16(r1, bf);
      float r2 = r1 - bf;
      pc[j] = rne16(r2, cf);
    }
    uint4 va, vb, vc;
    va.x = pa[0] | (pa[1] << 16); va.y = pa[2] | (pa[3] << 16);
    va.z = pa[4] | (pa[5] << 16); va.w = pa[6] | (pa[7] << 16);
    vb.x = pb[0] | (pb[1] << 16); vb.y = pb[2] | (pb[3] << 16);
    vb.z = pb[4] | (pb[5] << 16); vb.w = pb[6] | (pb[7] << 16);
    vc.x = pc[0] | (pc[1] << 16); vc.y = pc[2] | (pc[3] << 16);
    vc.z = pc[4] | (pc[5] << 16); vc.w = pc[6] | (pc[7] << 16);
    *(uint4*)(hb + g * 8) = va;
    *(uint4*)(hb + C + g * 8) = vb;
    *(uint4*)(hcp + g * 8) = vc;
  }
  sqout[row] = sq;
}

// ---------------- knn(k=8): 2-plane MFMA candidate scan -> top-12 per (row,quarter) -------
// quarter-OUTER grid order (L2 locality: resident blocks share one quarter's columns).
// dot ~= aa*ba + ab*bb + aa*bb + ab*ba (4 MFMAs, err ~2^-16 rel) — superset only;
// exact fp32 re-rank happens in knn8rf.
template <int C>
__global__ __launch_bounds__(256, 4) void knn8_kernel(const ushortT* __restrict__ hab,
                                                      const float* __restrict__ sqh,
                                                      u64* __restrict__ plist) {
  static_assert(C == 64 || C == 128, "C");
  constexpr int STR = 2 * C + 8;                 // ushorts/col; quad-stride odd (33/17)
  constexpr int BSB = 64 * STR * 2;
  constexpr int SMB = BSB > 32768 ? BSB : 32768; // merge buffer needs 32KB
  __shared__ __align__(16) unsigned char smem[SMB];
  ushortT* Bs = (ushortT*)smem;
  u64* mb = (u64*)smem;
  __shared__ float sqB[64];

  const int t = threadIdx.x;
  const int l = t & 63, w = t >> 6;
  const int quad = l >> 4, fif = l & 15;
  const int quarter = blockIdx.x >> 8, rg = blockIdx.x & 255;
  const int rowBase = rg * 64;
  const int batchBase = rowBase & ~(NPTS - 1);

  constexpr int KS = C / 32;
  short8 aa[KS], ab[KS];
  {
    const int arow = rowBase + 16 * w + fif;
    const ushortT* ap = hab + (size_t)arow * (2 * C);
    #pragma unroll
    for (int s = 0; s < KS; ++s) {
      aa[s] = *(const short8*)(ap + s * 32 + quad * 8);
      ab[s] = *(const short8*)(ap + C + s * 32 + quad * 8);
    }
  }
  float sqA[4];
  #pragma unroll
  for (int r = 0; r < 4; ++r) sqA[r] = sqh[rowBase + 16 * w + quad * 4 + r];

  u64 L[4][8];
  #pragma unroll
  for (int r = 0; r < 4; ++r)
    #pragma unroll
    for (int z = 0; z < 8; ++z) L[r][z] = ~0ULL;

  constexpr int CH = C / 4;                      // 16B chunks per col (2 planes)
  constexpr int LOG = (CH == 32) ? 5 : 4;

  for (int chunk = 0; chunk < 32; ++chunk) {
    const int cb = quarter * 2048 + chunk * 64;
    __syncthreads();
    {
      #pragma unroll
      for (int z = 0; z < (64 * CH) / 256; ++z) {
        int id = t + 256 * z;
        int col = id >> LOG, ch = id & (CH - 1);
        uint4 v = *(const uint4*)(hab + (size_t)(batchBase + cb + col) * (2 * C) + ch * 8);
        *(uint4*)(Bs + col * STR + ch * 8) = v;
      }
      if (t < 64) sqB[t] = sqh[batchBase + cb + t];
    }
    __syncthreads();
    #pragma unroll
    for (int tile = 0; tile < 4; ++tile) {
      const int lcol = tile * 16 + fif;
      f32x4 acc0 = {0.f, 0.f, 0.f, 0.f};
      f32x4 acc1 = {0.f, 0.f, 0.f, 0.f};
      const ushortT* bp = Bs + lcol * STR + quad * 8;
      #pragma unroll
      for (int s = 0; s < KS; ++s) {
        short8 ba = *(const short8*)(bp + s * 32);
        short8 bb = *(const short8*)(bp + C + s * 32);
        acc0 = __builtin_amdgcn_mfma_f32_16x16x32_bf16(aa[s], ba, acc0, 0, 0, 0);
        acc1 = __builtin_amdgcn_mfma_f32_16x16x32_bf16(aa[s], bb, acc1, 0, 0, 0);
        acc0 = __builtin_amdgcn_mfma_f32_16x16x32_bf16(ab[s], bb, acc0, 0, 0, 0);
        acc1 = __builtin_amdgcn_mfma_f32_16x16x32_bf16(ab[s], ba, acc1, 0, 0, 0);
      }
      const float sb = sqB[lcol];
      const unsigned gcol = (unsigned)(cb + lcol);
      #pragma unroll
      for (int r = 0; r < 4; ++r) {
        float dot = acc0[r] + acc1[r];
        float d = sqA[r] + sb - 2.0f * dot;
        u64 key = ((u64)fkey(d) << 16) | gcol;
        chain_insert<8>(L[r], key);
      }
    }
  }
  // 16-way merge per row -> top-12, two 32-row passes (mb aliases Bs)
  for (int rh = 0; rh < 2; ++rh) {
    __syncthreads();
    if ((w >> 1) == rh) {
      #pragma unroll
      for (int r = 0; r < 4; ++r) {
        int lr = (16 * w + quad * 4 + r) & 31;
        #pragma unroll
        for (int z = 0; z < 8; ++z) mb[(lr * 16 + fif) * 8 + z] = L[r][z];
      }
    }
    __syncthreads();
    if (t < 32) {
      int ps[16];
      #pragma unroll
      for (int s = 0; s < 16; ++s) ps[s] = 0;
      u64 outk[12];
      for (int z = 0; z < 12; ++z) {
        u64 best = ~0ULL; int bs = 0;
        #pragma unroll
        for (int s = 0; s < 16; ++s) {
          u64 v = (ps[s] < 8) ? mb[(t * 16 + s) * 8 + ps[s]] : ~0ULL;
          if (v < best) { best = v; bs = s; }
        }
        outk[z] = best;
        #pragma unroll
        for (int s = 0; s < 16; ++s) ps[s] += (s == bs);
      }
      u64* dst = plist + ((size_t)(rowBase + rh * 32 + t) * 4 + quarter) * 12;
      #pragma unroll
      for (int z = 0; z < 12; ++z) dst[z] = outk[z];
    }
  }
}

// ---------------- exact fp32 re-rank of 48 candidates + top-8 + fused gather-max ----------
template <int C>
__global__ __launch_bounds__(256) void knn8rf_kernel(const u64* __restrict__ plist,
                                                     const ushortT* __restrict__ hab,
                                                     const ushortT* __restrict__ hc,
                                                     const float* __restrict__ sqh,
                                                     float* __restrict__ nout) {
  __shared__ float xiL[4][C];
  const int t = threadIdx.x;
  const int w = t >> 6, l = t & 63;
  const int row = blockIdx.x * 4 + w;
  const int batchBase = row & ~(NPTS - 1);
  {
    const ushortT* sab = hab + (size_t)row * (2 * C);
    const ushortT* sc = hc + (size_t)row * C;
    #pragma unroll
    for (int u = 0; u < C / 64; ++u) {
      int ch = l + u * 64;
      float av = bf2f(sab[ch]), bv = bf2f(sab[C + ch]), cv = bf2f(sc[ch]);
      xiL[w][ch] = av + (bv + cv);
    }
  }
  __syncthreads();
  const float sqi = sqh[row];
  const u64* pl = plist + (size_t)row * 48;
  u64 myk = ~0ULL;
  if (l < 48) {
    int cand = (int)(pl[l] & 0xFFFFULL) & (NPTS - 1);
    const ushortT* sab = hab + (size_t)(batchBase + cand) * (2 * C);
    const ushortT* sc = hc + (size_t)(batchBase + cand) * C;
    float dot = 0.f;
    #pragma unroll 4
    for (int kk = 0; kk < C; kk += 2) {
      unsigned ua = *(const unsigned*)(sab + kk);
      unsigned ub = *(const unsigned*)(sab + C + kk);
      unsigned uc = *(const unsigned*)(sc + kk);
      float a0 = __uint_as_float(ua << 16), a1 = __uint_as_float(ua & 0xFFFF0000u);
      float b0 = __uint_as_float(ub << 16), b1 = __uint_as_float(ub & 0xFFFF0000u);
      float c0 = __uint_as_float(uc << 16), c1 = __uint_as_float(uc & 0xFFFF0000u);
      float x0 = a0 + (b0 + c0), x1 = a1 + (b1 + c1);
      dot = fmaf(xiL[w][kk], x0, dot);
      dot = fmaf(xiL[w][kk + 1], x1, dot);
    }
    float d = sqi + sqh[batchBase + cand] - 2.0f * dot;
    myk = ((u64)fkey(d) << 16) | (unsigned)cand;
  }
  u64 top[8];
  #pragma unroll
  for (int z = 0; z < 8; ++z) {
    u64 m = myk;
    #pragma unroll
    for (int off = 1; off < 64; off <<= 1) {
      u64 o = (u64)__shfl_xor((long long)m, off);
      m = o < m ? o : m;
    }
    top[z] = m;
    if (myk == m) myk = ~0ULL;
  }
  constexpr int PER = C / 64;
  float mx[PER];
  #pragma unroll
  for (int u = 0; u < PER; ++u) mx[u] = -FLT_MAX;
  #pragma unroll
  for (int z = 0; z < 8; ++z) {
    int idx = (int)(top[z] & 0xFFFFULL) & (NPTS - 1);
    const ushortT* sab = hab + (size_t)(batchBase + idx) * (2 * C);
    const ushortT* sc = hc + (size_t)(batchBase + idx) * C;
    #pragma unroll
    for (int u = 0; u < PER; ++u) {
      int ch = l + u * 64;
      float av = bf2f(sab[ch]), bv = bf2f(sab[C + ch]), cv = bf2f(sc[ch]);
      float xv = av + (bv + cv);
      mx[u] = fmaxf(mx[u], xv);
    }
  }
  float* dst = nout + (size_t)row * C;
  #pragma unroll
  for (int u = 0; u < PER; ++u) dst[l + u * 64] = mx[u];
}

// ---------------- n2[16384,128] @ gW2[128,1024]: deterministic stats partials + atomicMax ----------------
__global__ __launch_bounds__(256) void mmE_kernel(const float* __restrict__ n2,
                                                  const float* __restrict__ W,
                                                  float* __restrict__ psum,
                                                  float* __restrict__ psq,
                                                  unsigned* __restrict__ gmax) {
  __shared__ __align__(16) float As[64 * 64];
  __shared__ __align__(16) float Bs[64 * 64];
  __shared__ float sP[16 * 64];
  __shared__ float qP[16 * 64];
  __shared__ float mP[16 * 64];
  const int t = threadIdx.x;
  const int rowStripe = blockIdx.x >> 4;
  const int colStripe = blockIdx.x & 15;
  const int rowBase = rowStripe * 64;
  const int colBase = colStripe * 64;
  const int batch = rowBase >> 13;
  const int tx = t & 15, ty = t >> 4;

  float acc[16];
  #pragma unroll
  for (int q = 0; q < 16; ++q) acc[q] = 0.f;

  for (int kh = 0; kh < 2; ++kh) {
    __syncthreads();
    {
      const int ar = t & 63;
      const int k0 = (t >> 6) * 16;
      const float* src = n2 + (size_t)(rowBase + ar) * 128 + kh * 64 + k0;
      #pragma unroll
      for (int kk = 0; kk < 16; kk += 4) {
        float4 v = *(const float4*)(src + kk);
        As[(k0 + kk + 0) * 64 + ar] = v.x;
        As[(k0 + kk + 1) * 64 + ar] = v.y;
        As[(k0 + kk + 2) * 64 + ar] = v.z;
        As[(k0 + kk + 3) * 64 + ar] = v.w;
      }
    }
    {
      #pragma unroll
      for (int z = 0; z < 4; ++z) {
        int u = t + 256 * z;
        int k = u >> 4, c4 = u & 15;
        float4 v = *(const float4*)(W + (size_t)(kh * 64 + k) * 1024 + colBase + c4 * 4);
        *(float4*)(Bs + k * 64 + c4 * 4) = v;
      }
    }
    __syncthreads();
    #pragma unroll 4
    for (int k = 0; k < 64; ++k) {
      float4 a4 = *(const float4*)(As + k * 64 + ty * 4);
      float4 b4 = *(const float4*)(Bs + k * 64 + tx * 4);
      acc[0] = fmaf(a4.x, b4.x, acc[0]);   acc[1] = fmaf(a4.x, b4.y, acc[1]);
      acc[2] = fmaf(a4.x, b4.z, acc[2]);   acc[3] = fmaf(a4.x, b4.w, acc[3]);
      acc[4] = fmaf(a4.y, b4.x, acc[4]);   acc[5] = fmaf(a4.y, b4.y, acc[5]);
      acc[6] = fmaf(a4.y, b4.z, acc[6]);   acc[7] = fmaf(a4.y, b4.w, acc[7]);
      acc[8] = fmaf(a4.z, b4.x, acc[8]);   acc[9] = fmaf(a4.z, b4.y, acc[9]);
      acc[10] = fmaf(a4.z, b4.z, acc[10]); acc[11] = fmaf(a4.z, b4.w, acc[11]);
      acc[12] = fmaf(a4.w, b4.x, acc[12]); acc[13] = fmaf(a4.w, b4.y, acc[13]);
      acc[14] = fmaf(a4.w, b4.z, acc[14]); acc[15] = fmaf(a4.w, b4.w, acc[15]);
    }
  }
  #pragma unroll
  for (int p = 0; p < 4; ++p) {
    float s = 0.f, q = 0.f, m = -FLT_MAX;
    #pragma unroll
    for (int qq = 0; qq < 4; ++qq) {
      float v = acc[qq * 4 + p];
      s += v; q = fmaf(v, v, q); m = fmaxf(m, v);
    }
    sP[ty * 64 + tx * 4 + p] = s;
    qP[ty * 64 + tx * 4 + p] = q;
    mP[ty * 64 + tx * 4 + p] = m;
  }
  __syncthreads();
  if (t < 64) {
    float s = 0.f, q = 0.f, m = -FLT_MAX;
    #pragma unroll
    for (int u = 0; u < 16; ++u) {
      s += sP[u * 64 + t];
      q += qP[u * 64 + t];
      m = fmaxf(m, mP[u * 64 + t]);
    }
    psum[rowStripe * 1024 + colBase + t] = s;
    psq [rowStripe * 1024 + colBase + t] = q;
    atomicMax(&gmax[batch * 1024 + colBase + t], fkey(m));
  }
}

// ---------------- BN4 finalize (deterministic stripe sum) + leaky on pooled max ----------------
__global__ void poolbn_kernel(const float* __restrict__ psumE, const float* __restrict__ psqE,
                              const unsigned* __restrict__ gmax,
                              const float* __restrict__ gg2, const float* __restrict__ gb2,
                              float* __restrict__ fpool) {
  int c = threadIdx.x;
  float s = 0.f, q = 0.f;
  for (int bb = 0; bb < 256; ++bb) { s += psumE[bb * 1024 + c]; q += psqE[bb * 1024 + c]; }
  float m = s * (1.f / 16384.f);
  float v = q * (1.f / 16384.f) - m * m;
  float sc = gg2[c] * rsqrtf(v + 1e-5f);
  float sh = gb2[c] - m * sc;
  #pragma unroll
  for (int b = 0; b < 2; ++b) {
    float raw = fdecode(gmax[b * 1024 + c]);
    float t = fmaf(raw, sc, sh);
    fpool[b * 1024 + c] = t > 0.f ? t : 0.01f * t;
  }
}

// ---------------- fpool @ W4 + BN over 2 samples + relu -> out ----------------
__global__ __launch_bounds__(64) void final_kernel(const float* __restrict__ fpool,
                                                   const float* __restrict__ W4,
                                                   const float* __restrict__ g4,
                                                   const float* __restrict__ b4f,
                                                   float* __restrict__ out) {
  const int o = blockIdx.x * 64 + threadIdx.x;
  float a0 = 0.f, a1 = 0.f;
  for (int c = 0; c < 1024; ++c) {
    float w = W4[(size_t)c * 512 + o];
    a0 = fmaf(fpool[c], w, a0);
    a1 = fmaf(fpool[1024 + c], w, a1);
  }
  float m = 0.5f * (a0 + a1);
  float d0 = a0 - m, d1 = a1 - m;
  float v = 0.5f * (d0 * d0 + d1 * d1);
  float r = rsqrtf(v + 1e-5f);
  float o0 = fmaf(d0 * r, g4[o], b4f[o]);
  float o1 = fmaf(d1 * r, g4[o], b4f[o]);
  out[o] = fmaxf(o0, 0.f);
  out[512 + o] = fmaxf(o1, 0.f);
}

extern "C" void kernel_launch(void* const* d_in, const int* in_sizes, int n_in,
                              void* d_out, int out_size, void* d_ws, size_t ws_size,
                              hipStream_t stream) {
  (void)in_sizes; (void)n_in; (void)out_size; (void)ws_size;
  const float* x   = (const float*)d_in[0];
  const float* W1  = (const float*)d_in[1];
  const float* g1  = (const float*)d_in[2];
  const float* b1  = (const float*)d_in[3];
  const float* W2  = (const float*)d_in[4];
  const float* g2  = (const float*)d_in[5];
  const float* b2  = (const float*)d_in[6];
  const float* W3  = (const float*)d_in[7];
  const float* g3  = (const float*)d_in[8];
  const float* b3  = (const float*)d_in[9];
  const float* gW1 = (const float*)d_in[10];
  const float* gg1 = (const float*)d_in[11];
  const float* gb1 = (const float*)d_in[12];
  const float* gW2 = (const float*)d_in[13];
  const float* gg2 = (const float*)d_in[14];
  const float* gb2 = (const float*)d_in[15];
  const float* W4  = (const float*)d_in[16];
  const float* g4  = (const float*)d_in[17];
  const float* b4  = (const float*)d_in[18];
  float* out = (float*)d_out;
  float* ws = (float*)d_ws;

  // footprint identical to the R4-proven 30.49 MB layout
  float* sqx  = ws;                    // 16384
  float* feat = sqx + 16384;           // 196608 (later: p2/p3/p4 stats)
  float* bufA = feat + 196608;         // 1048576
  float* bufB = bufA + 1048576;        // 1048576 (bufA+bufB also hold plist 6.3MB)
  float* sqh  = bufB + 1048576;        // 16384
  float* sqg  = sqh + 16384;           // 16384
  float* ygr  = sqg + 16384;           // 2097152 (yg1 raw -> n2)
  float* hbfR = ygr + 2097152;         // 3145728 (hab+hc [+n1]; layer2 overwrites)
  float* st   = hbfR + 3145728;

  unsigned* gmax = (unsigned*)(st);            // 2048 uints
  float* scale0 = st + 2048;  float* shift0 = st + 2112;
  float* scale1 = st + 2176;  float* shift1 = st + 2240;
  float* scale2 = st + 2304;  float* shift2 = st + 2368;
  float* scale3 = st + 2432;  float* shift3 = st + 2560;
  float* fpool  = st + 2688;                   // 2048
  float* p1s    = st + 4736;                   // 256*64
  float* p1q    = p1s + 16384;                 // ends st+37504

  float* p2s = feat;             float* p2q = feat + 16384;
  float* p3s = feat + 32768;     float* p3q = feat + 49152;
  float* p4s = feat;             float* p4q = feat + 32768;     // reused after p2/p3 dead
  float* pEs = bufA;             float* pEq = bufA + 262144;
  u64* plist = (u64*)bufA;                     // 16384*48 u64 = 6.3MB (bufA+bufB span)

  // layer-1 (C=64): hab1 = 16384 x 128 us (4MB), hc1 = 16384 x 64 us (2MB), n1 after (4MB)
  ushortT* hab1 = (ushortT*)hbfR;
  ushortT* hc1  = (ushortT*)(hbfR + 1048576);
  float*   n1   = hbfR + 1572864;
  // layer-2 (C=128): hab2 = 8MB, hc2 = 4MB — overwrites layer-1 region entirely
  ushortT* hab2 = (ushortT*)hbfR;
  ushortT* hc2  = (ushortT*)(hbfR + 2097152);
  float*   n2   = ygr;

  hipMemsetAsync(gmax, 0, 2048 * sizeof(unsigned), stream);
  sqx_kernel<<<64, 256, 0, stream>>>(x, sqx);
  knn32_cov_kernel<<<512, 512, 0, stream>>>(x, sqx, feat);
  mm12_64_kernel<<<256, 64, 0, stream>>>(feat, W1, bufA, p1s, p1q);
  finP_kernel<64><<<1, 64, 0, stream>>>(p1s, p1q, g1, b1, scale0, shift0);
  mm64_kernel<64, true><<<256, 64, 0, stream>>>(bufA, W2, scale0, shift0, bufB, p2s, p2q);
  finP_kernel<64><<<1, 64, 0, stream>>>(p2s, p2q, g2, b2, scale1, shift1);
  mm64_kernel<64, true><<<256, 64, 0, stream>>>(bufB, W3, scale1, shift1, bufA, p3s, p3q);
  finP_kernel<64><<<1, 64, 0, stream>>>(p3s, p3q, g3, b3, scale2, shift2);
  apply_kernel<64, false><<<64, 256, 0, stream>>>(bufA, scale2, shift2, hab1, hc1, sqh);
  knn8_kernel<64><<<1024, 256, 0, stream>>>(hab1, sqh, plist);
  knn8rf_kernel<64><<<4096, 256, 0, stream>>>(plist, hab1, hc1, sqh, n1);
  mm64_kernel<128, false><<<256, 64, 0, stream>>>(n1, gW1, scale0, shift0, ygr, p4s, p4q);
  finP_kernel<128><<<1, 128, 0, stream>>>(p4s, p4q, gg1, gb1, scale3, shift3);
  apply_kernel<128, true><<<64, 256, 0, stream>>>(ygr, scale3, shift3, hab2, hc2, sqg);
  knn8_kernel<128><<<1024, 256, 0, stream>>>(hab2, sqg, plist);
  knn8rf_kernel<128><<<4096, 256, 0, stream>>>(plist, hab2, hc2, sqg, n2);
  mmE_kernel<<<4096, 256, 0, stream>>>(n2, gW2, pEs, pEq, gmax);
  poolbn_kernel<<<1, 1024, 0, stream>>>(pEs, pEq, gmax, gg2, gb2, fpool);
  final_kernel<<<8, 64, 0, stream>>>(fpool, W4, g4, b4, out);
}